// Round 10
// baseline (239.426 us; speedup 1.0000x reference)
//
#include <hip/hip_runtime.h>
#include <hip/hip_bf16.h>

#define BATCH 4
#define NTOK 4096
#define CDIM 128
#define KSCALE 0.02254211001389005f   // log2(e)/64  (scale = 1/sqrt(4096), ref quirk)

typedef __bf16 bf16;
typedef __bf16 bf16x8 __attribute__((ext_vector_type(8)));
typedef __bf16 bf16x4 __attribute__((ext_vector_type(4)));
typedef float  f32x4  __attribute__((ext_vector_type(4)));

// K tile image (64 token-rows x 128 ch): 8-elem segments, XOR-swizzled (R4/R6-verified).
__device__ __forceinline__ int koff(int r, int c) {
    return (r * 16 + (((c >> 3) ^ r ^ (r >> 2)) & 15)) * 8 + (c & 7);
}
// V tile image slot layout (R4-verified address math; slot semantics permuted via pinv)
__device__ __forceinline__ int voff(int d, int s) {
    return ((s >> 3) * 128 + (d ^ (s >> 3))) * 8 + (s & 7);
}
// kv permutation (R7-verified): slot t holds kv pi(t); pinv(kv) = slot.
__device__ __forceinline__ int pinv(int kv) {
    return (kv & 32) + ((kv & 12) << 1) + ((kv >> 2) & 4) + (kv & 3);
}

__device__ __forceinline__ void dma16(const bf16* g, bf16* l) {
    __builtin_amdgcn_global_load_lds(
        (const __attribute__((address_space(1))) unsigned int*)g,
        (__attribute__((address_space(3))) unsigned int*)l, 16, 0, 0);
}

// ---------------------------------------------------------------------------
// Projection (R7/R9-verified math). R10: V-image scatter packed as b64
// (pinv preserves kv&3, so i=0..3 land in contiguous slots -> bf16x4 write).
// grid (64 n-tiles, B, 3), block 256.
// ---------------------------------------------------------------------------
__global__ __launch_bounds__(256) void proj_kernel(
    const float* __restrict__ x, const float* __restrict__ Wq,
    const float* __restrict__ Wk, const float* __restrict__ Wv,
    bf16* __restrict__ Qg, bf16* __restrict__ Kg, bf16* __restrict__ Vtg)
{
    __shared__ bf16 t_s[64 * 132];    // x tile transposed; reused as output image
    __shared__ bf16 w_s[128 * 128];   // W, segment-swizzled

    const int tid = threadIdx.x;
    const int b = blockIdx.y, n0 = blockIdx.x * 64, m = blockIdx.z;
    const float* W = (m == 0) ? Wq : (m == 1) ? Wk : Wv;

    {   // stage x[b,:,n0:n0+64] transposed -> t_s[n][c]
        const float* xb = x + (size_t)b * CDIM * NTOK + n0;
        const int n = tid & 63, cg4 = tid >> 6;
#pragma unroll
        for (int g = 0; g < 8; ++g) {
            const int c0 = g * 16 + cg4 * 4;
            float v0 = xb[(size_t)(c0 + 0) * NTOK + n];
            float v1 = xb[(size_t)(c0 + 1) * NTOK + n];
            float v2 = xb[(size_t)(c0 + 2) * NTOK + n];
            float v3 = xb[(size_t)(c0 + 3) * NTOK + n];
            bf16x4 t = {(bf16)v0, (bf16)v1, (bf16)v2, (bf16)v3};
            *(bf16x4*)&t_s[n * 132 + c0] = t;
        }
    }
    {   // stage W swizzled (R2-verified, 0 conflicts)
#pragma unroll
        for (int it = 0; it < 16; ++it) {
            const int idx = it * 1024 + tid * 4;
            const int d = idx >> 7, c = idx & 127;
            const float4 v = *(const float4*)(W + d * 128 + c);
            bf16x4 t = {(bf16)v.x, (bf16)v.y, (bf16)v.z, (bf16)v.w};
            *(bf16x4*)&w_s[(d * 16 + (((c >> 3) ^ d) & 15)) * 8 + (c & 7)] = t;
        }
    }
    __syncthreads();

    const int lane = tid & 63, wv = tid >> 6;
    const int l16 = lane & 15, quad = lane >> 4;

    bf16x8 af[4];
#pragma unroll
    for (int kc = 0; kc < 4; ++kc)
        af[kc] = *(const bf16x8*)&t_s[(wv * 16 + l16) * 132 + kc * 32 + quad * 8];
    __syncthreads();                 // t_s free -> output image
    bf16* img = t_s;

    const int vslot0 = pinv(wv * 16 + quad * 4);   // i=0..3 contiguous from here

#pragma unroll
    for (int dblk = 0; dblk < 8; ++dblk) {
        f32x4 acc = {0.f, 0.f, 0.f, 0.f};
#pragma unroll
        for (int kc = 0; kc < 4; ++kc) {
            const int seg = (dblk * 16 + l16) * 16 + (((kc * 4 + quad) ^ l16) & 15);
            acc = __builtin_amdgcn_mfma_f32_16x16x32_bf16(
                af[kc], *(const bf16x8*)&w_s[seg * 8], acc, 0, 0, 0);
        }
        const int c = dblk * 16 + l16;              // channel
        if (m == 2) {
            bf16x4 t = {(bf16)acc[0], (bf16)acc[1], (bf16)acc[2], (bf16)acc[3]};
            *(bf16x4*)&img[voff(c, vslot0)] = t;    // b64 packed scatter
        } else {
#pragma unroll
            for (int i = 0; i < 4; ++i) {
                const int r = wv * 16 + quad * 4 + i;
                img[koff(r, c)] = (bf16)acc[i];
            }
        }
    }
    __syncthreads();

    if (m == 0) {   // unswizzle -> Qg linear
        const int r = tid >> 2, q4 = tid & 3;
        bf16* dst = Qg + ((size_t)b * NTOK + n0 + r) * CDIM + q4 * 32;
#pragma unroll
        for (int j = 0; j < 4; ++j)
            *(bf16x8*)(dst + j * 8) = *(const bf16x8*)&img[koff(r, q4 * 32 + j * 8)];
    } else {        // dump image verbatim (attn DMAs halves linearly)
        bf16* dst = ((m == 1) ? Kg : Vtg) + ((size_t)b * 64 + blockIdx.x) * 8192 + tid * 32;
#pragma unroll
        for (int j = 0; j < 4; ++j)
            *(bf16x8*)(dst + j * 8) = *(const bf16x8*)&img[tid * 32 + j * 8];
    }
}

// ---------------------------------------------------------------------------
// Flash attention, no-max softmax, S^T/in-lane-P (R7/R8-verified math),
// NoAlias 4-buffer pipeline (R9-verified). R10: 32-row KV tiles -> 8 KB
// buffers, LDS 32 KB -> 4 blocks/CU (16 waves). Half-tile swizzle algebra:
// odd half => rsw ^= 8 (koff's r>>2 term), PV d-xor ^= 4 (voff's s>>3 term);
// kt0 even => the adjustment is a compile-time 0/8 per unrolled sub-iter.
// nsplit=8 -> grid 1024 = 4/CU single round, ktn=16 (32-row tiles).
// ---------------------------------------------------------------------------
#define ISSUE_TILE32(kt_, KARR, VARR)                                        \
    do {                                                                     \
        const size_t ib_ = ((size_t)b * 64 + ((kt_) >> 1)) * 8192            \
                           + ((kt_) & 1) * 4096;                             \
        _Pragma("unroll")                                                    \
        for (int i_ = 0; i_ < 2; ++i_) {                                     \
            const int off_ = (wv * 2 + i_) * 512 + doff;                     \
            dma16(Kg + ib_ + off_, &KARR[off_]);                             \
        }                                                                    \
        _Pragma("unroll")                                                    \
        for (int i_ = 0; i_ < 2; ++i_) {                                     \
            const int off_ = (wv * 2 + i_) * 512 + doff;                     \
            dma16(Vtg + ib_ + off_, &VARR[off_]);                            \
        }                                                                    \
    } while (0)

#define COMPUTE_TILE32(KARR, VARR, HADJ)                                     \
    do {                                                                     \
        bf16x8 pb0, pb1;                                                     \
        _Pragma("unroll")                                                    \
        for (int nb = 0; nb < 2; ++nb) {                                     \
            const int rr  = nb * 16 + l16;                                   \
            const int rsw = ((rr ^ (rr >> 2)) & 15) ^ (HADJ);                \
            f32x4 s0 = {0.f,0.f,0.f,0.f}, s1 = {0.f,0.f,0.f,0.f};            \
            _Pragma("unroll")                                                \
            for (int kc = 0; kc < 4; ++kc) {                                 \
                bf16x8 bk = *(const bf16x8*)&KARR[(rr * 16 +                 \
                    (((kc * 4 + quad) ^ rsw) & 15)) * 8];                    \
                s0 = __builtin_amdgcn_mfma_f32_16x16x32_bf16(bk, af[0][kc], s0, 0, 0, 0); \
                s1 = __builtin_amdgcn_mfma_f32_16x16x32_bf16(bk, af[1][kc], s1, 0, 0, 0); \
            }                                                                \
            _Pragma("unroll")                                                \
            for (int i = 0; i < 4; ++i) {                                    \
                float p0 = __builtin_amdgcn_exp2f(s0[i] * KSCALE); ls[0] += p0; \
                float p1 = __builtin_amdgcn_exp2f(s1[i] * KSCALE); ls[1] += p1; \
                pb0[nb * 4 + i] = (bf16)p0;                                  \
                pb1[nb * 4 + i] = (bf16)p1;                                  \
            }                                                                \
        }                                                                    \
        _Pragma("unroll")                                                    \
        for (int d = 0; d < 8; ++d) {                                        \
            bf16x8 bv = *(const bf16x8*)&VARR[(quad * 128 +                  \
                ((d * 16 + l16) ^ quad ^ ((HADJ) >> 1))) * 8];               \
            o[0][d] = __builtin_amdgcn_mfma_f32_16x16x32_bf16(bv, pb0, o[0][d], 0, 0, 0); \
            o[1][d] = __builtin_amdgcn_mfma_f32_16x16x32_bf16(bv, pb1, o[1][d], 0, 0, 0); \
        }                                                                    \
    } while (0)

__global__ __launch_bounds__(256, 4) void attn_kernel(
    const bf16* __restrict__ Qg, const bf16* __restrict__ Kg,
    const bf16* __restrict__ Vtg, bf16* __restrict__ Op,
    float* __restrict__ lsum, int nsplit)
{
    __shared__ bf16 kA[4096];
    __shared__ bf16 kB[4096];
    __shared__ bf16 vA[4096];
    __shared__ bf16 vB[4096];

    const int tid = threadIdx.x;
    int qb, b, sp;
    if (nsplit >= 2) {      // XCD-aware decode (R8-verified)
        const int id  = blockIdx.x;
        const int xcd = id & 7, t = id >> 3;
        qb = t & 31;
        const int combo = xcd + 8 * (t >> 5);
        b = combo & 3; sp = combo >> 2;
    } else {
        qb = blockIdx.x & 31; b = (blockIdx.x >> 5) & 3; sp = 0;
    }
    const int q0 = qb * 128;
    const int lane = tid & 63, wv = tid >> 6;
    const int l16 = lane & 15, quad = lane >> 4;

    const int ktn = 128 / nsplit;      // 32-row tiles; even for nsplit 1/2/4/8
    const int kt0 = sp * ktn;          // always even

    bf16x8 af[2][4];
#pragma unroll
    for (int rb = 0; rb < 2; ++rb)
#pragma unroll
        for (int kc = 0; kc < 4; ++kc)
            af[rb][kc] = *(const bf16x8*)&Qg[((size_t)b * NTOK + q0 + wv * 32 + rb * 16 + l16) * CDIM
                                             + kc * 32 + quad * 8];

    f32x4 o[2][8];
#pragma unroll
    for (int rb = 0; rb < 2; ++rb)
#pragma unroll
        for (int d = 0; d < 8; ++d) o[rb][d] = (f32x4){0.f, 0.f, 0.f, 0.f};
    float ls[2] = {0.f, 0.f};

    const int doff = lane * 8;

    ISSUE_TILE32(kt0, kA, vA);         // prologue -> A (even tile, HADJ=0)

    for (int j = 0; j < ktn; j += 2) {
        // ---- even sub-iter: compute kt0+j (A, half=0), prefetch j+1 -> B ----
        __builtin_amdgcn_sched_barrier(0);
        __builtin_amdgcn_s_barrier();              // everyone done reading B
        __builtin_amdgcn_sched_barrier(0);
        if (j + 1 < ktn) ISSUE_TILE32(kt0 + j + 1, kB, vB);
        __builtin_amdgcn_sched_barrier(0);
        if (j + 1 < ktn) __builtin_amdgcn_s_waitcnt(0xF74);  // vmcnt(4): A landed
        else             __builtin_amdgcn_s_waitcnt(0xF70);  // vmcnt(0)
        __builtin_amdgcn_s_barrier();              // all waves' A landed
        __builtin_amdgcn_sched_barrier(0);
        COMPUTE_TILE32(kA, vA, 0);

        // ---- odd sub-iter: compute kt0+j+1 (B, half=1), prefetch j+2 -> A ----
        __builtin_amdgcn_sched_barrier(0);
        __builtin_amdgcn_s_barrier();              // everyone done reading A
        __builtin_amdgcn_sched_barrier(0);
        if (j + 2 < ktn) ISSUE_TILE32(kt0 + j + 2, kA, vA);
        __builtin_amdgcn_sched_barrier(0);
        if (j + 2 < ktn) __builtin_amdgcn_s_waitcnt(0xF74);  // vmcnt(4): B landed
        else             __builtin_amdgcn_s_waitcnt(0xF70);
        __builtin_amdgcn_s_barrier();              // all waves' B landed
        __builtin_amdgcn_sched_barrier(0);
        COMPUTE_TILE32(kB, vB, 8);
        __builtin_amdgcn_sched_barrier(0);
    }

    // ls: column (qrow) sums — reduce over quads (lanes 16,32 apart)
#pragma unroll
    for (int rb = 0; rb < 2; ++rb) {
        ls[rb] += __shfl_xor(ls[rb], 16, 64);
        ls[rb] += __shfl_xor(ls[rb], 32, 64);
    }
    if (lane < 16) {
#pragma unroll
        for (int rb = 0; rb < 2; ++rb)
            lsum[(size_t)sp * (BATCH * NTOK) + (size_t)b * NTOK
                 + q0 + wv * 32 + rb * 16 + lane] = ls[rb];
    }
    // Partials: O^T fragments, [sp][qb][b][wv][rb][dblk][lane][i] (b64 coalesced)
    bf16* op = Op + (((((size_t)sp * 32 + qb) * BATCH + b) * 4 + wv) * 4096);
#pragma unroll
    for (int rb = 0; rb < 2; ++rb)
#pragma unroll
        for (int d = 0; d < 8; ++d) {
            bf16x4 t = {(bf16)o[rb][d][0], (bf16)o[rb][d][1],
                        (bf16)o[rb][d][2], (bf16)o[rb][d][3]};
            *(bf16x4*)&op[((rb * 8 + d) * 64 + lane) * 4] = t;
        }
}

// ---------------------------------------------------------------------------
// Combine (R7-verified, unchanged): out = sum_sp(Op) / sum_sp(lsum).
// ---------------------------------------------------------------------------
__global__ __launch_bounds__(256) void combine_kernel(
    const bf16* __restrict__ Op, const float* __restrict__ lsum,
    float* __restrict__ out, int nsplit)
{
    const int g  = blockIdx.x * 256 + threadIdx.x;   // [0, 524288)
    const int rg = g >> 5;                           // global row [0,16384)
    const int cl = (g & 31) << 2;                    // d base 0,4,...,124
    const int b  = rg >> 12, n = rg & 4095;
    const int qb = n >> 7, wv = (n >> 5) & 3, rb = (n >> 4) & 1, l16 = n & 15;
    const int dblk = cl >> 4, quad = (cl >> 2) & 3;

    const size_t base = (((size_t)qb * BATCH + b) * 4 + wv) * 4096
                        + (size_t)((rb * 8 + dblk) * 64 + quad * 16 + l16) * 4;
    const size_t spstride = (size_t)32 * BATCH * 4 * 4096;  // 2M elems

    float a0 = 0.f, a1 = 0.f, a2 = 0.f, a3 = 0.f;
    for (int s = 0; s < nsplit; ++s) {
        bf16x4 v = *(const bf16x4*)&Op[(size_t)s * spstride + base];
        a0 += (float)v[0]; a1 += (float)v[1]; a2 += (float)v[2]; a3 += (float)v[3];
    }
    float l = 0.f;
    for (int s = 0; s < nsplit; ++s)
        l += lsum[(size_t)s * (BATCH * NTOK) + rg];
    const float inv = 1.0f / l;
    f32x4 r = {a0 * inv, a1 * inv, a2 * inv, a3 * inv};
    *(f32x4*)&out[(size_t)rg * CDIM + cl] = r;
}

// ---------------------------------------------------------------------------
extern "C" void kernel_launch(void* const* d_in, const int* in_sizes, int n_in,
                              void* d_out, int out_size, void* d_ws, size_t ws_size,
                              hipStream_t stream)
{
    const float* x  = (const float*)d_in[0];
    const float* Wq = (const float*)d_in[1];
    const float* Wk = (const float*)d_in[2];
    const float* Wv = (const float*)d_in[3];
    float* out = (float*)d_out;

    // ws: Q 4M | Kimg 4M | Vimg 4M | lsum 512K | Op nsplit*4M (bf16)
    char* ws = (char*)d_ws;
    bf16*  Qg   = (bf16*)ws;
    bf16*  Kg   = (bf16*)(ws + (4u << 20));
    bf16*  Vtg  = (bf16*)(ws + (8u << 20));
    float* lsum = (float*)(ws + (12u << 20));
    bf16*  Op   = (bf16*)(ws + (12u << 20) + (512u << 10));

    const size_t base = (12u << 20) + (512u << 10);
    const size_t MB4  = 4u << 20;
    // nsplit=8 -> grid 1024 = 4 blocks/CU x 256 CUs (32 KB LDS), single round
    int nsplit = (ws_size >= base + 8 * MB4) ? 8
               : (ws_size >= base + 4 * MB4) ? 4
               : (ws_size >= base + 2 * MB4) ? 2 : 1;

    hipLaunchKernelGGL(proj_kernel, dim3(64, BATCH, 3), dim3(256), 0, stream,
                       x, Wq, Wk, Wv, Qg, Kg, Vtg);
    hipLaunchKernelGGL(attn_kernel, dim3(32 * BATCH * nsplit), dim3(256), 0, stream,
                       Qg, Kg, Vtg, Op, lsum, nsplit);
    hipLaunchKernelGGL(combine_kernel, dim3(2048), dim3(256), 0, stream,
                       Op, lsum, out, nsplit);
}

// Round 11
// 117.441 us; speedup vs baseline: 2.0387x; 2.0387x over previous
//
#include <hip/hip_runtime.h>
#include <hip/hip_bf16.h>

#define BATCH 4
#define NTOK 4096
#define CDIM 128
#define KSCALE 0.02254211001389005f   // log2(e)/64  (scale = 1/sqrt(4096), ref quirk)

typedef __bf16 bf16;
typedef __bf16 bf16x8 __attribute__((ext_vector_type(8)));
typedef __bf16 bf16x4 __attribute__((ext_vector_type(4)));
typedef float  f32x4  __attribute__((ext_vector_type(4)));

// K tile image (64 token-rows x 128 ch): 8-elem segments, XOR-swizzled (R4/R6-verified).
__device__ __forceinline__ int koff(int r, int c) {
    return (r * 16 + (((c >> 3) ^ r ^ (r >> 2)) & 15)) * 8 + (c & 7);
}
// V tile image slot layout (R4-verified address math; slot semantics permuted via pinv)
__device__ __forceinline__ int voff(int d, int s) {
    return ((s >> 3) * 128 + (d ^ (s >> 3))) * 8 + (s & 7);
}
// kv permutation (R7-verified): slot t holds kv pi(t); pinv(kv) = slot.
__device__ __forceinline__ int pinv(int kv) {
    return (kv & 32) + ((kv & 12) << 1) + ((kv >> 2) & 4) + (kv & 3);
}

__device__ __forceinline__ void dma16(const bf16* g, bf16* l) {
    __builtin_amdgcn_global_load_lds(
        (const __attribute__((address_space(1))) unsigned int*)g,
        (__attribute__((address_space(3))) unsigned int*)l, 16, 0, 0);
}

// ---------------------------------------------------------------------------
// Projection (R9-verified math + R10's verified b64 V-scatter).
// grid (64 n-tiles, B, 3), block 256. LDS ~49 KB -> 3 blocks/CU.
// ---------------------------------------------------------------------------
__global__ __launch_bounds__(256) void proj_kernel(
    const float* __restrict__ x, const float* __restrict__ Wq,
    const float* __restrict__ Wk, const float* __restrict__ Wv,
    bf16* __restrict__ Qg, bf16* __restrict__ Kg, bf16* __restrict__ Vtg)
{
    __shared__ bf16 t_s[64 * 132];    // x tile transposed; reused as output image
    __shared__ bf16 w_s[128 * 128];   // W, segment-swizzled

    const int tid = threadIdx.x;
    const int b = blockIdx.y, n0 = blockIdx.x * 64, m = blockIdx.z;
    const float* W = (m == 0) ? Wq : (m == 1) ? Wk : Wv;

    {   // stage x[b,:,n0:n0+64] transposed -> t_s[n][c]
        const float* xb = x + (size_t)b * CDIM * NTOK + n0;
        const int n = tid & 63, cg4 = tid >> 6;
#pragma unroll
        for (int g = 0; g < 8; ++g) {
            const int c0 = g * 16 + cg4 * 4;
            float v0 = xb[(size_t)(c0 + 0) * NTOK + n];
            float v1 = xb[(size_t)(c0 + 1) * NTOK + n];
            float v2 = xb[(size_t)(c0 + 2) * NTOK + n];
            float v3 = xb[(size_t)(c0 + 3) * NTOK + n];
            bf16x4 t = {(bf16)v0, (bf16)v1, (bf16)v2, (bf16)v3};
            *(bf16x4*)&t_s[n * 132 + c0] = t;
        }
    }
    {   // stage W swizzled (R2-verified, 0 conflicts)
#pragma unroll
        for (int it = 0; it < 16; ++it) {
            const int idx = it * 1024 + tid * 4;
            const int d = idx >> 7, c = idx & 127;
            const float4 v = *(const float4*)(W + d * 128 + c);
            bf16x4 t = {(bf16)v.x, (bf16)v.y, (bf16)v.z, (bf16)v.w};
            *(bf16x4*)&w_s[(d * 16 + (((c >> 3) ^ d) & 15)) * 8 + (c & 7)] = t;
        }
    }
    __syncthreads();

    const int lane = tid & 63, wv = tid >> 6;
    const int l16 = lane & 15, quad = lane >> 4;

    bf16x8 af[4];
#pragma unroll
    for (int kc = 0; kc < 4; ++kc)
        af[kc] = *(const bf16x8*)&t_s[(wv * 16 + l16) * 132 + kc * 32 + quad * 8];
    __syncthreads();                 // t_s free -> output image
    bf16* img = t_s;

    const int vslot0 = pinv(wv * 16 + quad * 4);   // i=0..3 contiguous from here

#pragma unroll
    for (int dblk = 0; dblk < 8; ++dblk) {
        f32x4 acc = {0.f, 0.f, 0.f, 0.f};
#pragma unroll
        for (int kc = 0; kc < 4; ++kc) {
            const int seg = (dblk * 16 + l16) * 16 + (((kc * 4 + quad) ^ l16) & 15);
            acc = __builtin_amdgcn_mfma_f32_16x16x32_bf16(
                af[kc], *(const bf16x8*)&w_s[seg * 8], acc, 0, 0, 0);
        }
        const int c = dblk * 16 + l16;              // channel
        if (m == 2) {
            bf16x4 t = {(bf16)acc[0], (bf16)acc[1], (bf16)acc[2], (bf16)acc[3]};
            *(bf16x4*)&img[voff(c, vslot0)] = t;    // b64 packed scatter
        } else {
#pragma unroll
            for (int i = 0; i < 4; ++i) {
                const int r = wv * 16 + quad * 4 + i;
                img[koff(r, c)] = (bf16)acc[i];
            }
        }
    }
    __syncthreads();

    if (m == 0) {   // unswizzle -> Qg linear
        const int r = tid >> 2, q4 = tid & 3;
        bf16* dst = Qg + ((size_t)b * NTOK + n0 + r) * CDIM + q4 * 32;
#pragma unroll
        for (int j = 0; j < 4; ++j)
            *(bf16x8*)(dst + j * 8) = *(const bf16x8*)&img[koff(r, q4 * 32 + j * 8)];
    } else {        // dump image verbatim (attn DMAs it linearly)
        bf16* dst = ((m == 1) ? Kg : Vtg) + ((size_t)b * 64 + blockIdx.x) * 8192 + tid * 32;
#pragma unroll
        for (int j = 0; j < 4; ++j)
            *(bf16x8*)(dst + j * 8) = *(const bf16x8*)&img[tid * 32 + j * 8];
    }
}

// ---------------------------------------------------------------------------
// Flash attention — EXACT R9-verified configuration (best measured: attn
// below fill noise, FETCH 21 MB): 64-row KV tiles, four separate 16 KB
// __shared__ buffers (NoAlias -> compiler keeps prefetch in flight),
// K-loop unrolled x2 with static buffer roles, vmcnt(8) mid-loop waits.
// LDS 64 KB -> 2 blocks/CU; nsplit=4 -> grid 512 = 2/CU single round.
// L2 capacity lesson (R10): per-XCD resident footprint (Q 2 MB + streams
// 1 MB) must stay < 4 MB — this config sits at ~3 MB.
// ---------------------------------------------------------------------------
#define ISSUE_TILE(kt_, KARR, VARR)                                          \
    do {                                                                     \
        const bf16* Kt_ = Kg  + ((size_t)b * 64 + (kt_)) * 8192;             \
        const bf16* Vt_ = Vtg + ((size_t)b * 64 + (kt_)) * 8192;             \
        _Pragma("unroll")                                                    \
        for (int i_ = 0; i_ < 4; ++i_) {                                     \
            const int off_ = (wv * 4 + i_) * 512 + doff;                     \
            dma16(Kt_ + off_, &KARR[off_]);                                  \
        }                                                                    \
        _Pragma("unroll")                                                    \
        for (int i_ = 0; i_ < 4; ++i_) {                                     \
            const int off_ = (wv * 4 + i_) * 512 + doff;                     \
            dma16(Vt_ + off_, &VARR[off_]);                                  \
        }                                                                    \
    } while (0)

#define COMPUTE_TILE(KARR, VARR)                                             \
    do {                                                                     \
        bf16x8 pb[2][2];                                                     \
        _Pragma("unroll")                                                    \
        for (int nb = 0; nb < 4; ++nb) {                                     \
            const int rr  = nb * 16 + l16;                                   \
            const int rsw = (rr ^ (rr >> 2)) & 15;                           \
            f32x4 s0 = {0.f,0.f,0.f,0.f}, s1 = {0.f,0.f,0.f,0.f};            \
            _Pragma("unroll")                                                \
            for (int kc = 0; kc < 4; ++kc) {                                 \
                bf16x8 bk = *(const bf16x8*)&KARR[(rr * 16 +                 \
                    (((kc * 4 + quad) ^ rsw) & 15)) * 8];                    \
                s0 = __builtin_amdgcn_mfma_f32_16x16x32_bf16(bk, af[0][kc], s0, 0, 0, 0); \
                s1 = __builtin_amdgcn_mfma_f32_16x16x32_bf16(bk, af[1][kc], s1, 0, 0, 0); \
            }                                                                \
            const int kcn = nb >> 1, hoff = (nb & 1) * 4;                    \
            _Pragma("unroll")                                                \
            for (int i = 0; i < 4; ++i) {                                    \
                float p0 = __builtin_amdgcn_exp2f(s0[i] * KSCALE); ls[0] += p0; \
                float p1 = __builtin_amdgcn_exp2f(s1[i] * KSCALE); ls[1] += p1; \
                pb[0][kcn][hoff + i] = (bf16)p0;                             \
                pb[1][kcn][hoff + i] = (bf16)p1;                             \
            }                                                                \
        }                                                                    \
        _Pragma("unroll")                                                    \
        for (int kc = 0; kc < 2; ++kc) {                                     \
            const int kvg = kc * 4 + quad;                                   \
            _Pragma("unroll")                                                \
            for (int d = 0; d < 8; ++d) {                                    \
                bf16x8 bv = *(const bf16x8*)&VARR[(kvg * 128 +               \
                    ((d * 16 + l16) ^ kvg)) * 8];                            \
                o[0][d] = __builtin_amdgcn_mfma_f32_16x16x32_bf16(bv, pb[0][kc], o[0][d], 0, 0, 0); \
                o[1][d] = __builtin_amdgcn_mfma_f32_16x16x32_bf16(bv, pb[1][kc], o[1][d], 0, 0, 0); \
            }                                                                \
        }                                                                    \
    } while (0)

__global__ __launch_bounds__(256, 2) void attn_kernel(
    const bf16* __restrict__ Qg, const bf16* __restrict__ Kg,
    const bf16* __restrict__ Vtg, bf16* __restrict__ Op,
    float* __restrict__ lsum, int nsplit)
{
    __shared__ bf16 kA[8192];
    __shared__ bf16 kB[8192];
    __shared__ bf16 vA[8192];
    __shared__ bf16 vB[8192];

    const int tid = threadIdx.x;
    int qb, b, sp;
    if (nsplit >= 2) {      // XCD-aware decode (R8-verified)
        const int id  = blockIdx.x;
        const int xcd = id & 7, t = id >> 3;
        qb = t & 31;
        const int combo = xcd + 8 * (t >> 5);
        b = combo & 3; sp = combo >> 2;
    } else {
        qb = blockIdx.x & 31; b = (blockIdx.x >> 5) & 3; sp = 0;
    }
    const int q0 = qb * 128;
    const int lane = tid & 63, wv = tid >> 6;
    const int l16 = lane & 15, quad = lane >> 4;

    const int ktn = 64 / nsplit;       // 16 / 32 / 64 — always even
    const int kt0 = sp * ktn;

    bf16x8 af[2][4];
#pragma unroll
    for (int rb = 0; rb < 2; ++rb)
#pragma unroll
        for (int kc = 0; kc < 4; ++kc)
            af[rb][kc] = *(const bf16x8*)&Qg[((size_t)b * NTOK + q0 + wv * 32 + rb * 16 + l16) * CDIM
                                             + kc * 32 + quad * 8];

    f32x4 o[2][8];
#pragma unroll
    for (int rb = 0; rb < 2; ++rb)
#pragma unroll
        for (int d = 0; d < 8; ++d) o[rb][d] = (f32x4){0.f, 0.f, 0.f, 0.f};
    float ls[2] = {0.f, 0.f};

    const int doff = lane * 8;

    ISSUE_TILE(kt0, kA, vA);           // prologue -> A

    for (int j = 0; j < ktn; j += 2) {
        // ---- even sub-iter: compute tile kt0+j on A, prefetch j+1 into B ----
        __builtin_amdgcn_sched_barrier(0);
        __builtin_amdgcn_s_barrier();              // everyone done reading B
        __builtin_amdgcn_sched_barrier(0);
        if (j + 1 < ktn) ISSUE_TILE(kt0 + j + 1, kB, vB);
        __builtin_amdgcn_sched_barrier(0);
        if (j + 1 < ktn) __builtin_amdgcn_s_waitcnt(0xF78);  // vmcnt(8): A landed
        else             __builtin_amdgcn_s_waitcnt(0xF70);  // vmcnt(0)
        __builtin_amdgcn_s_barrier();              // all waves' A landed
        __builtin_amdgcn_sched_barrier(0);
        COMPUTE_TILE(kA, vA);

        // ---- odd sub-iter: compute tile kt0+j+1 on B, prefetch j+2 into A ----
        __builtin_amdgcn_sched_barrier(0);
        __builtin_amdgcn_s_barrier();              // everyone done reading A
        __builtin_amdgcn_sched_barrier(0);
        if (j + 2 < ktn) ISSUE_TILE(kt0 + j + 2, kA, vA);
        __builtin_amdgcn_sched_barrier(0);
        if (j + 2 < ktn) __builtin_amdgcn_s_waitcnt(0xF78);  // vmcnt(8): B landed
        else             __builtin_amdgcn_s_waitcnt(0xF70);
        __builtin_amdgcn_s_barrier();              // all waves' B landed
        __builtin_amdgcn_sched_barrier(0);
        COMPUTE_TILE(kB, vB);
        __builtin_amdgcn_sched_barrier(0);
    }

    // ls: column (qrow) sums — reduce over quads (lanes 16,32 apart)
#pragma unroll
    for (int rb = 0; rb < 2; ++rb) {
        ls[rb] += __shfl_xor(ls[rb], 16, 64);
        ls[rb] += __shfl_xor(ls[rb], 32, 64);
    }
    if (lane < 16) {
#pragma unroll
        for (int rb = 0; rb < 2; ++rb)
            lsum[(size_t)sp * (BATCH * NTOK) + (size_t)b * NTOK
                 + q0 + wv * 32 + rb * 16 + lane] = ls[rb];
    }
    // Partials: O^T fragments, [sp][qb][b][wv][rb][dblk][lane][i] (b64 coalesced)
    bf16* op = Op + (((((size_t)sp * 32 + qb) * BATCH + b) * 4 + wv) * 4096);
#pragma unroll
    for (int rb = 0; rb < 2; ++rb)
#pragma unroll
        for (int d = 0; d < 8; ++d) {
            bf16x4 t = {(bf16)o[rb][d][0], (bf16)o[rb][d][1],
                        (bf16)o[rb][d][2], (bf16)o[rb][d][3]};
            *(bf16x4*)&op[((rb * 8 + d) * 64 + lane) * 4] = t;
        }
}

// ---------------------------------------------------------------------------
// Combine (R7-verified, unchanged): out = sum_sp(Op) / sum_sp(lsum).
// ---------------------------------------------------------------------------
__global__ __launch_bounds__(256) void combine_kernel(
    const bf16* __restrict__ Op, const float* __restrict__ lsum,
    float* __restrict__ out, int nsplit)
{
    const int g  = blockIdx.x * 256 + threadIdx.x;   // [0, 524288)
    const int rg = g >> 5;                           // global row [0,16384)
    const int cl = (g & 31) << 2;                    // d base 0,4,...,124
    const int b  = rg >> 12, n = rg & 4095;
    const int qb = n >> 7, wv = (n >> 5) & 3, rb = (n >> 4) & 1, l16 = n & 15;
    const int dblk = cl >> 4, quad = (cl >> 2) & 3;

    const size_t base = (((size_t)qb * BATCH + b) * 4 + wv) * 4096
                        + (size_t)((rb * 8 + dblk) * 64 + quad * 16 + l16) * 4;
    const size_t spstride = (size_t)32 * BATCH * 4 * 4096;  // 2M elems

    float a0 = 0.f, a1 = 0.f, a2 = 0.f, a3 = 0.f;
    for (int s = 0; s < nsplit; ++s) {
        bf16x4 v = *(const bf16x4*)&Op[(size_t)s * spstride + base];
        a0 += (float)v[0]; a1 += (float)v[1]; a2 += (float)v[2]; a3 += (float)v[3];
    }
    float l = 0.f;
    for (int s = 0; s < nsplit; ++s)
        l += lsum[(size_t)s * (BATCH * NTOK) + rg];
    const float inv = 1.0f / l;
    f32x4 r = {a0 * inv, a1 * inv, a2 * inv, a3 * inv};
    *(f32x4*)&out[(size_t)rg * CDIM + cl] = r;
}

// ---------------------------------------------------------------------------
extern "C" void kernel_launch(void* const* d_in, const int* in_sizes, int n_in,
                              void* d_out, int out_size, void* d_ws, size_t ws_size,
                              hipStream_t stream)
{
    const float* x  = (const float*)d_in[0];
    const float* Wq = (const float*)d_in[1];
    const float* Wk = (const float*)d_in[2];
    const float* Wv = (const float*)d_in[3];
    float* out = (float*)d_out;

    // ws: Q 4M | Kimg 4M | Vimg 4M | lsum 512K | Op nsplit*4M (bf16)
    char* ws = (char*)d_ws;
    bf16*  Qg   = (bf16*)ws;
    bf16*  Kg   = (bf16*)(ws + (4u << 20));
    bf16*  Vtg  = (bf16*)(ws + (8u << 20));
    float* lsum = (float*)(ws + (12u << 20));
    bf16*  Op   = (bf16*)(ws + (12u << 20) + (512u << 10));

    const size_t base = (12u << 20) + (512u << 10);
    const size_t MB4  = 4u << 20;
    // nsplit=4 -> grid 512 = 2 blocks/CU x 256 CUs (64 KB LDS), single round.
    // Do NOT raise to 8: R10 showed per-XCD L2 overflow (5+ MB > 4 MB) -> 16x
    // K/V over-fetch.
    int nsplit = (ws_size >= base + 4 * MB4) ? 4
               : (ws_size >= base + 2 * MB4) ? 2 : 1;

    hipLaunchKernelGGL(proj_kernel, dim3(64, BATCH, 3), dim3(256), 0, stream,
                       x, Wq, Wk, Wv, Qg, Kg, Vtg);
    hipLaunchKernelGGL(attn_kernel, dim3(32 * BATCH * nsplit), dim3(256), 0, stream,
                       Qg, Kg, Vtg, Op, lsum, nsplit);
    hipLaunchKernelGGL(combine_kernel, dim3(2048), dim3(256), 0, stream,
                       Op, lsum, out, nsplit);
}